// Round 3
// baseline (781.263 us; speedup 1.0000x reference)
//
#include <hip/hip_runtime.h>

#define T_STEPS 100
#define NTRAJ   8192
#define MBLK    16

typedef __attribute__((ext_vector_type(8))) _Float16 f16x8;
typedef __attribute__((ext_vector_type(4))) float    f32x4;

#define MFMA16(a, b, c) __builtin_amdgcn_mfma_f32_16x16x32_f16((a), (b), (c), 0, 0, 0)

// XOR swizzle on element index within a row (2B elems; XOR elem bits 3..5)
#define SWZ(row, col) ((col) ^ (((row) & 7) << 3))

__device__ __forceinline__ float fast_tanh(float x) {
    float e = __expf(2.f * x);
    return 1.f - 2.f * __builtin_amdgcn_rcpf(1.f + e);
}
__device__ __forceinline__ float fast_sigmoid(float x) {
    float e = __expf(-x);
    return __builtin_amdgcn_rcpf(1.f + e);
}

// ---------------------------------------------------------------------------
// Weight packing (unchanged): B-fragment tile order, 144 tiles of 512 f16.
// ---------------------------------------------------------------------------
__global__ void pack_kernel(const float* __restrict__ Wo1, const float* __restrict__ Wo2,
                            const float* __restrict__ Wz1, const float* __restrict__ Wz2,
                            const float* __restrict__ Wr1, const float* __restrict__ Wr2,
                            const float* __restrict__ Wh1, const float* __restrict__ Wh2,
                            _Float16* __restrict__ P)
{
    int idx = blockIdx.x * 256 + threadIdx.x;
    if (idx >= 144 * 512) return;
    int tile = idx >> 9;
    int r    = idx & 511;
    int lane = r >> 3, j = r & 7;
    int krel = ((lane >> 4) << 3) + j;   // 0..31
    int c16  = lane & 15;
    float val = 0.f;

    if (tile < 14) {                       // ODE L1
        int t = tile, nt = t >> 1, kt = t & 1;
        int k = kt * 32 + krel, n = nt * 16 + c16;
        if (k < 64 && n < 100) val = Wo1[k * 100 + n];
    } else if (tile < 30) {                // ODE L2
        int t = tile - 14, nt = t >> 2, kt = t & 3;
        int k = kt * 32 + krel, n = nt * 16 + c16;
        if (k < 100) val = Wo2[k * 64 + n];
    } else if (tile < 75) {                // ZR L1
        int t = tile - 30, nt = t / 3, kt = t % 3;
        int k = kt * 32 + krel;            // K = 96 exact
        if (nt < 7)      { int n = nt * 16 + c16;        if (n < 100) val = Wz1[k * 100 + n]; }
        else if (nt >= 8){ int n = (nt - 8) * 16 + c16;  if (n < 100) val = Wr1[k * 100 + n]; }
    } else if (tile < 107) {               // ZR L2
        int t = tile - 75, gate = t >> 4, rem = t & 15, nt = rem >> 2, kt = rem & 3;
        int k = kt * 32 + krel, n = nt * 16 + c16;
        const float* W = gate ? Wr2 : Wz2;
        if (k < 100) val = W[k * 64 + n];
    } else if (tile < 128) {               // H L1
        int t = tile - 107, nt = t / 3, kt = t % 3;
        int k = kt * 32 + krel, n = nt * 16 + c16;
        if (n < 100) val = Wh1[k * 100 + n];
    } else {                               // H L2
        int t = tile - 128, nt = t >> 2, kt = t & 3;
        int k = kt * 32 + krel, n = nt * 16 + c16;
        if (k < 100) val = Wh2[k * 64 + n];
    }
    P[idx] = (_Float16)val;
}

__device__ __forceinline__ f16x8 ldsA(const _Float16* buf, int stride, int row, int kcol) {
    return *(const f16x8*)(buf + row * stride + SWZ(row, kcol));
}

// ---------------------------------------------------------------------------
// Main kernel. Block = 16 trajectories, 512 threads = 8 waves.
// Waves 0-3 own the 64 state columns (y, yode, zg in registers) and run
// G2 / G4-z / G6; waves 4-7 run G4-r (yode via f32 LDS) and share G1/G3/G5.
// ---------------------------------------------------------------------------
__global__ __launch_bounds__(512, 4) void odernn_kernel(
    const float* __restrict__ data, const float* __restrict__ ts,
    const float* __restrict__ prior,
    const float* __restrict__ bo1, const float* __restrict__ bo2,
    const float* __restrict__ bz1, const float* __restrict__ bz2,
    const float* __restrict__ br1, const float* __restrict__ br2,
    const float* __restrict__ bh1, const float* __restrict__ bh2,
    const _Float16* __restrict__ P, float* __restrict__ out)
{
    __shared__ __align__(16) _Float16 sYb[MBLK * 64];   // y (f16), G1 A input
    __shared__ __align__(16) _Float16 sYX[MBLK * 128];  // [yode | x]
    __shared__ __align__(16) _Float16 sRX[MBLK * 128];  // [rg*yode | x]
    __shared__ __align__(16) _Float16 sH1[MBLK * 128];  // hidden (ODE L1 / H L1)
    __shared__ __align__(16) _Float16 sZR[MBLK * 256];  // [z-hidden(112)+pad | r-hidden(112)+pad]
    __shared__ float sYO[MBLK * 64];                    // yode f32, for r-gate waves

    const int tid  = threadIdx.x;
    const int lane = tid & 63;
    const int wv   = tid >> 6;            // 0..7
    const int c16  = lane & 15;
    const int g4   = lane >> 4;
    const int m0   = blockIdx.x * MBLK;
    const f16x8* Pt = (const f16x8*)P;

    // ---- per-wave tile ownership ----
    const int colw = (wv & 3) * 16 + c16;   // state column for waves 0-3; r-tile col for 4-7

    // ---- preload biases ----
    float b_o1 = 0.f, b_h1 = 0.f, b_zr0 = 0.f, b_zr1 = 0.f;
    if (wv < 7) {
        int c = wv * 16 + c16;
        if (c < 100) { b_o1 = bo1[c]; b_h1 = bh1[c]; }
    }
    {   // G3 tile A: t = wv (z if wv<7, r if wv==7); tile B: t = wv+8 (r), wv<6
        if (wv < 7) { int c = wv * 16 + c16; if (c < 100) b_zr0 = bz1[c]; }
        else        { b_zr0 = br1[c16]; }
        if (wv < 6) { int bc = (wv + 1) * 16 + c16; if (bc < 100) b_zr1 = br1[bc]; }
    }
    float b_o2 = 0.f, b_z2 = 0.f, b_h2 = 0.f, b_r2 = 0.f;
    if (wv < 4) { b_o2 = bo2[colw]; b_z2 = bz2[colw]; b_h2 = bh2[colw]; }
    else        { b_r2 = br2[colw]; }

    // ---- preload B-fragments for short phases ----
    f16x8 Bo1[2], Bo2[4], Bh2[4], Bzr[4];
    if (wv < 7) {
        Bo1[0] = Pt[(wv * 2 + 0) * 64 + lane];
        Bo1[1] = Pt[(wv * 2 + 1) * 64 + lane];
    }
    if (wv < 4) {
        #pragma unroll
        for (int kt = 0; kt < 4; ++kt) {
            Bo2[kt] = Pt[(14 + wv * 4 + kt) * 64 + lane];
            Bh2[kt] = Pt[(128 + wv * 4 + kt) * 64 + lane];
        }
    }
    {
        int base = (wv < 4) ? (75 + wv * 4) : (91 + (wv - 4) * 4);
        #pragma unroll
        for (int kt = 0; kt < 4; ++kt) Bzr[kt] = Pt[(base + kt) * 64 + lane];
    }

    // ---- init ----
    float y[4] = {0.f, 0.f, 0.f, 0.f};
    if (wv < 4) {
        #pragma unroll
        for (int r = 0; r < 4; ++r) {
            int row = g4 * 4 + r;
            y[r] = prior[(size_t)(m0 + row) * 64 + colw];
            sYb[row * 64 + SWZ(row, colw)] = (_Float16)y[r];
        }
    }
    if (tid < 256) {
        int row = tid >> 4, col = 112 + (tid & 15);
        sH1[row * 128 + SWZ(row, col)] = (_Float16)0.f;
    }
    {
        int row = tid >> 5, cc = tid & 31;
        int col = (cc < 16) ? (112 + cc) : (224 + cc);
        sZR[row * 256 + SWZ(row, col)] = (_Float16)0.f;
    }
    __syncthreads();

    const float t0 = ts[0], t1 = ts[1];

    // running pointer for this thread's x element (row = tid>>5, c = tid&31), t = s+1
    const int xrow = tid >> 5, xc = tid & 31;
    const float* xptr = data + (size_t)(m0 + xrow) * (T_STEPS * 32) + 32 + xc;
    const int xsw = xrow * 128 + SWZ(xrow, 64 + xc);

    #pragma unroll 1
    for (int s = 0; s < T_STEPS - 1; ++s) {
        const float dt = (s == 0) ? (t1 - t0) : (ts[s - 1] - ts[s]);
        float xv = *xptr; xptr += 32;

        // ---- G1: H1 = tanh(y @ Wo1 + bo1)  — wave w<7 owns tile nt=w ----
        if (wv < 7) {
            f16x8 a0 = ldsA(sYb, 64, c16, (g4 << 3));
            f16x8 a1 = ldsA(sYb, 64, c16, 32 + (g4 << 3));
            f32x4 z4 = {0.f, 0.f, 0.f, 0.f};
            f32x4 acc0 = MFMA16(a0, Bo1[0], z4);
            f32x4 acc1 = MFMA16(a1, Bo1[1], z4);
            int col = wv * 16 + c16;
            #pragma unroll
            for (int r = 0; r < 4; ++r) {
                int row = g4 * 4 + r;
                sH1[row * 128 + SWZ(row, col)] = (_Float16)fast_tanh(acc0[r] + acc1[r] + b_o1);
            }
        }
        // stage x into both concat buffers (one elem per thread)
        {
            _Float16 xh = (_Float16)xv;
            sYX[xsw] = xh; sRX[xsw] = xh;
        }
        __syncthreads();

        // ---- G2: yode = y + dt*(H1 @ Wo2 + bo2) — waves 0-3 ----
        float yo[4] = {0.f, 0.f, 0.f, 0.f};
        if (wv < 4) {
            f32x4 z4 = {0.f, 0.f, 0.f, 0.f};
            f32x4 acc0 = z4, acc1 = z4;
            acc0 = MFMA16(ldsA(sH1, 128, c16, 0 * 32 + (g4 << 3)), Bo2[0], acc0);
            acc1 = MFMA16(ldsA(sH1, 128, c16, 1 * 32 + (g4 << 3)), Bo2[1], acc1);
            acc0 = MFMA16(ldsA(sH1, 128, c16, 2 * 32 + (g4 << 3)), Bo2[2], acc0);
            acc1 = MFMA16(ldsA(sH1, 128, c16, 3 * 32 + (g4 << 3)), Bo2[3], acc1);
            #pragma unroll
            for (int r = 0; r < 4; ++r) {
                int row = g4 * 4 + r;
                yo[r] = y[r] + dt * (acc0[r] + acc1[r] + b_o2);
                sYO[row * 64 + colw] = yo[r];
                sYX[row * 128 + SWZ(row, colw)] = (_Float16)yo[r];
            }
        }
        __syncthreads();

        // ---- G3: zr-hidden = tanh([yode|x] @ W{z,r}1 + b) — tiles {wv, wv+8} ----
        {
            f16x8 a0 = ldsA(sYX, 128, c16, 0 * 32 + (g4 << 3));
            f16x8 a1 = ldsA(sYX, 128, c16, 1 * 32 + (g4 << 3));
            f16x8 a2 = ldsA(sYX, 128, c16, 2 * 32 + (g4 << 3));
            f32x4 z4 = {0.f, 0.f, 0.f, 0.f};
            {   // tile A: t = wv
                int bt = (wv < 7) ? wv : wv + 1;
                f32x4 acc0 = MFMA16(a0, Pt[(30 + bt * 3 + 0) * 64 + lane], z4);
                f32x4 acc1 = MFMA16(a1, Pt[(30 + bt * 3 + 1) * 64 + lane], z4);
                acc0 = MFMA16(a2, Pt[(30 + bt * 3 + 2) * 64 + lane], acc0);
                int col = bt * 16 + c16;
                #pragma unroll
                for (int r = 0; r < 4; ++r) {
                    int row = g4 * 4 + r;
                    sZR[row * 256 + SWZ(row, col)] = (_Float16)fast_tanh(acc0[r] + acc1[r] + b_zr0);
                }
            }
            if (wv < 6) {   // tile B: t = wv+8 (always r-gate), bt = t+1
                int bt = wv + 9;
                f32x4 acc0 = MFMA16(a0, Pt[(30 + bt * 3 + 0) * 64 + lane], z4);
                f32x4 acc1 = MFMA16(a1, Pt[(30 + bt * 3 + 1) * 64 + lane], z4);
                acc0 = MFMA16(a2, Pt[(30 + bt * 3 + 2) * 64 + lane], acc0);
                int col = bt * 16 + c16;
                #pragma unroll
                for (int r = 0; r < 4; ++r) {
                    int row = g4 * 4 + r;
                    sZR[row * 256 + SWZ(row, col)] = (_Float16)fast_tanh(acc0[r] + acc1[r] + b_zr1);
                }
            }
        }
        __syncthreads();

        // ---- G4: z-gate (waves 0-3, into regs) ; r-gate (waves 4-7, into sRX) ----
        float zg[4] = {0.f, 0.f, 0.f, 0.f};
        {
            int half = (wv < 4) ? 0 : 128;
            f32x4 z4 = {0.f, 0.f, 0.f, 0.f};
            f32x4 acc0 = z4, acc1 = z4;
            acc0 = MFMA16(ldsA(sZR, 256, c16, half + 0 * 32 + (g4 << 3)), Bzr[0], acc0);
            acc1 = MFMA16(ldsA(sZR, 256, c16, half + 1 * 32 + (g4 << 3)), Bzr[1], acc1);
            acc0 = MFMA16(ldsA(sZR, 256, c16, half + 2 * 32 + (g4 << 3)), Bzr[2], acc0);
            acc1 = MFMA16(ldsA(sZR, 256, c16, half + 3 * 32 + (g4 << 3)), Bzr[3], acc1);
            if (wv < 4) {
                #pragma unroll
                for (int r = 0; r < 4; ++r) zg[r] = fast_sigmoid(acc0[r] + acc1[r] + b_z2);
            } else {
                #pragma unroll
                for (int r = 0; r < 4; ++r) {
                    int row = g4 * 4 + r;
                    float yov = sYO[row * 64 + colw];
                    float rv = fast_sigmoid(acc0[r] + acc1[r] + b_r2) * yov;
                    sRX[row * 128 + SWZ(row, colw)] = (_Float16)rv;
                }
            }
        }
        __syncthreads();

        // ---- G5: H1 = tanh([rg*yode|x] @ Wh1 + bh1) — wave w<7 owns tile nt=w ----
        if (wv < 7) {
            f16x8 a0 = ldsA(sRX, 128, c16, 0 * 32 + (g4 << 3));
            f16x8 a1 = ldsA(sRX, 128, c16, 1 * 32 + (g4 << 3));
            f16x8 a2 = ldsA(sRX, 128, c16, 2 * 32 + (g4 << 3));
            f32x4 z4 = {0.f, 0.f, 0.f, 0.f};
            f32x4 acc0 = MFMA16(a0, Pt[(107 + wv * 3 + 0) * 64 + lane], z4);
            f32x4 acc1 = MFMA16(a1, Pt[(107 + wv * 3 + 1) * 64 + lane], z4);
            acc0 = MFMA16(a2, Pt[(107 + wv * 3 + 2) * 64 + lane], acc0);
            int col = wv * 16 + c16;
            #pragma unroll
            for (int r = 0; r < 4; ++r) {
                int row = g4 * 4 + r;
                sH1[row * 128 + SWZ(row, col)] = (_Float16)fast_tanh(acc0[r] + acc1[r] + b_h1);
            }
        }
        __syncthreads();

        // ---- G6: h = tanh(H1 @ Wh2 + bh2); y = (1-z)*h + z*yode — waves 0-3 ----
        if (wv < 4) {
            f32x4 z4 = {0.f, 0.f, 0.f, 0.f};
            f32x4 acc0 = z4, acc1 = z4;
            acc0 = MFMA16(ldsA(sH1, 128, c16, 0 * 32 + (g4 << 3)), Bh2[0], acc0);
            acc1 = MFMA16(ldsA(sH1, 128, c16, 1 * 32 + (g4 << 3)), Bh2[1], acc1);
            acc0 = MFMA16(ldsA(sH1, 128, c16, 2 * 32 + (g4 << 3)), Bh2[2], acc0);
            acc1 = MFMA16(ldsA(sH1, 128, c16, 3 * 32 + (g4 << 3)), Bh2[3], acc1);
            #pragma unroll
            for (int r = 0; r < 4; ++r) {
                int row = g4 * 4 + r;
                float h = fast_tanh(acc0[r] + acc1[r] + b_h2);
                y[r] = (1.f - zg[r]) * h + zg[r] * yo[r];
                sYb[row * 64 + SWZ(row, colw)] = (_Float16)y[r];
            }
        }
        __syncthreads();
    }

    if (wv < 4) {
        #pragma unroll
        for (int r = 0; r < 4; ++r) {
            int row = g4 * 4 + r;
            out[(size_t)(m0 + row) * 64 + colw] = y[r];
        }
    }
}

extern "C" void kernel_launch(void* const* d_in, const int* in_sizes, int n_in,
                              void* d_out, int out_size, void* d_ws, size_t ws_size,
                              hipStream_t stream) {
    const float* data = (const float*)d_in[0];
    const float* ts   = (const float*)d_in[1];
    const float* prior= (const float*)d_in[2];
    const float* Wo1 = (const float*)d_in[3];  const float* bo1 = (const float*)d_in[4];
    const float* Wo2 = (const float*)d_in[5];  const float* bo2 = (const float*)d_in[6];
    const float* Wz1 = (const float*)d_in[7];  const float* bz1 = (const float*)d_in[8];
    const float* Wz2 = (const float*)d_in[9];  const float* bz2 = (const float*)d_in[10];
    const float* Wr1 = (const float*)d_in[11]; const float* br1 = (const float*)d_in[12];
    const float* Wr2 = (const float*)d_in[13]; const float* br2 = (const float*)d_in[14];
    const float* Wh1 = (const float*)d_in[15]; const float* bh1 = (const float*)d_in[16];
    const float* Wh2 = (const float*)d_in[17]; const float* bh2 = (const float*)d_in[18];
    _Float16* P = (_Float16*)d_ws;
    float* out = (float*)d_out;

    hipLaunchKernelGGL(pack_kernel, dim3((144 * 512 + 255) / 256), dim3(256), 0, stream,
                       Wo1, Wo2, Wz1, Wz2, Wr1, Wr2, Wh1, Wh2, P);
    hipLaunchKernelGGL(odernn_kernel, dim3(NTRAJ / MBLK), dim3(512), 0, stream,
                       data, ts, prior, bo1, bo2, bz1, bz2, br1, br2, bh1, bh2, P, out);
}

// Round 4
// 498.699 us; speedup vs baseline: 1.5666x; 1.5666x over previous
//
#include <hip/hip_runtime.h>

#define T_STEPS 100
#define NTRAJ   8192
#define MBLK    16

typedef __attribute__((ext_vector_type(8))) _Float16 f16x8;
typedef __attribute__((ext_vector_type(4))) float    f32x4;

#define MFMA16(a, b, c) __builtin_amdgcn_mfma_f32_16x16x32_f16((a), (b), (c), 0, 0, 0)

// XOR swizzle on element index within a row (2B elems; XOR elem bits 3..5)
#define SWZ(row, col) ((col) ^ (((row) & 7) << 3))

__device__ __forceinline__ float fast_tanh(float x) {
    float e = __expf(2.f * x);
    return 1.f - 2.f * __builtin_amdgcn_rcpf(1.f + e);
}
__device__ __forceinline__ float fast_sigmoid(float x) {
    float e = __expf(-x);
    return __builtin_amdgcn_rcpf(1.f + e);
}

// ---------------------------------------------------------------------------
// Weight packing (unchanged): B-fragment tile order, 144 tiles of 512 f16.
// ---------------------------------------------------------------------------
__global__ void pack_kernel(const float* __restrict__ Wo1, const float* __restrict__ Wo2,
                            const float* __restrict__ Wz1, const float* __restrict__ Wz2,
                            const float* __restrict__ Wr1, const float* __restrict__ Wr2,
                            const float* __restrict__ Wh1, const float* __restrict__ Wh2,
                            _Float16* __restrict__ P)
{
    int idx = blockIdx.x * 256 + threadIdx.x;
    if (idx >= 144 * 512) return;
    int tile = idx >> 9;
    int r    = idx & 511;
    int lane = r >> 3, j = r & 7;
    int krel = ((lane >> 4) << 3) + j;   // 0..31
    int c16  = lane & 15;
    float val = 0.f;

    if (tile < 14) {                       // ODE L1
        int t = tile, nt = t >> 1, kt = t & 1;
        int k = kt * 32 + krel, n = nt * 16 + c16;
        if (k < 64 && n < 100) val = Wo1[k * 100 + n];
    } else if (tile < 30) {                // ODE L2
        int t = tile - 14, nt = t >> 2, kt = t & 3;
        int k = kt * 32 + krel, n = nt * 16 + c16;
        if (k < 100) val = Wo2[k * 64 + n];
    } else if (tile < 75) {                // ZR L1
        int t = tile - 30, nt = t / 3, kt = t % 3;
        int k = kt * 32 + krel;            // K = 96 exact
        if (nt < 7)      { int n = nt * 16 + c16;        if (n < 100) val = Wz1[k * 100 + n]; }
        else if (nt >= 8){ int n = (nt - 8) * 16 + c16;  if (n < 100) val = Wr1[k * 100 + n]; }
    } else if (tile < 107) {               // ZR L2
        int t = tile - 75, gate = t >> 4, rem = t & 15, nt = rem >> 2, kt = rem & 3;
        int k = kt * 32 + krel, n = nt * 16 + c16;
        const float* W = gate ? Wr2 : Wz2;
        if (k < 100) val = W[k * 64 + n];
    } else if (tile < 128) {               // H L1
        int t = tile - 107, nt = t / 3, kt = t % 3;
        int k = kt * 32 + krel, n = nt * 16 + c16;
        if (n < 100) val = Wh1[k * 100 + n];
    } else {                               // H L2
        int t = tile - 128, nt = t >> 2, kt = t & 3;
        int k = kt * 32 + krel, n = nt * 16 + c16;
        if (k < 100) val = Wh2[k * 64 + n];
    }
    P[idx] = (_Float16)val;
}

__device__ __forceinline__ f16x8 ldsA(const _Float16* buf, int stride, int row, int kcol) {
    return *(const f16x8*)(buf + row * stride + SWZ(row, kcol));
}

// ---------------------------------------------------------------------------
// Main kernel. Block = 16 trajectories, 512 threads = 8 waves.
// Waves 0-3 own the 64 state columns (y, yode, zg in registers) and run
// G2 / G4-z / G6; waves 4-7 run G4-r (yode via f32 LDS) and share G1/G3/G5.
// launch_bounds (512,2): 256-VGPR cap -> no forced spills (round-2 lesson).
// ---------------------------------------------------------------------------
__global__ __launch_bounds__(512, 2) void odernn_kernel(
    const float* __restrict__ data, const float* __restrict__ ts,
    const float* __restrict__ prior,
    const float* __restrict__ bo1, const float* __restrict__ bo2,
    const float* __restrict__ bz1, const float* __restrict__ bz2,
    const float* __restrict__ br1, const float* __restrict__ br2,
    const float* __restrict__ bh1, const float* __restrict__ bh2,
    const _Float16* __restrict__ P, float* __restrict__ out)
{
    __shared__ __align__(16) _Float16 sYb[MBLK * 64];   // y (f16), G1 A input
    __shared__ __align__(16) _Float16 sYX[MBLK * 128];  // [yode | x]
    __shared__ __align__(16) _Float16 sRX[MBLK * 128];  // [rg*yode | x]
    __shared__ __align__(16) _Float16 sH1[MBLK * 128];  // hidden (ODE L1 / H L1)
    __shared__ __align__(16) _Float16 sZR[MBLK * 256];  // [z-hidden(112)+pad | r-hidden(112)+pad]
    __shared__ float sYO[MBLK * 64];                    // yode f32, for r-gate waves

    const int tid  = threadIdx.x;
    const int lane = tid & 63;
    const int wv   = tid >> 6;            // 0..7
    const int c16  = lane & 15;
    const int g4   = lane >> 4;
    const int m0   = blockIdx.x * MBLK;
    const f16x8* Pt = (const f16x8*)P;

    // ---- per-wave tile ownership ----
    const int colw = (wv & 3) * 16 + c16;   // state column for waves 0-3; r-tile col for 4-7

    // ---- preload biases ----
    float b_o1 = 0.f, b_h1 = 0.f, b_zr0 = 0.f, b_zr1 = 0.f;
    if (wv < 7) {
        int c = wv * 16 + c16;
        if (c < 100) { b_o1 = bo1[c]; b_h1 = bh1[c]; }
    }
    {   // G3 tile A: t = wv (z if wv<7, r if wv==7); tile B: t = wv+8 (r), wv<6
        if (wv < 7) { int c = wv * 16 + c16; if (c < 100) b_zr0 = bz1[c]; }
        else        { b_zr0 = br1[c16]; }
        if (wv < 6) { int bc = (wv + 1) * 16 + c16; if (bc < 100) b_zr1 = br1[bc]; }
    }
    float b_o2 = 0.f, b_z2 = 0.f, b_h2 = 0.f, b_r2 = 0.f;
    if (wv < 4) { b_o2 = bo2[colw]; b_z2 = bz2[colw]; b_h2 = bh2[colw]; }
    else        { b_r2 = br2[colw]; }

    // ---- preload B-fragments ONLY for short dependent phases G2/G4/G6 ----
    f16x8 Bo2[4], Bh2[4], Bzr[4];
    if (wv < 4) {
        #pragma unroll
        for (int kt = 0; kt < 4; ++kt) {
            Bo2[kt] = Pt[(14 + wv * 4 + kt) * 64 + lane];
            Bh2[kt] = Pt[(128 + wv * 4 + kt) * 64 + lane];
        }
    }
    {
        int base = (wv < 4) ? (75 + wv * 4) : (91 + (wv - 4) * 4);
        #pragma unroll
        for (int kt = 0; kt < 4; ++kt) Bzr[kt] = Pt[(base + kt) * 64 + lane];
    }

    // ---- init ----
    float y[4] = {0.f, 0.f, 0.f, 0.f};
    if (wv < 4) {
        #pragma unroll
        for (int r = 0; r < 4; ++r) {
            int row = g4 * 4 + r;
            y[r] = prior[(size_t)(m0 + row) * 64 + colw];
            sYb[row * 64 + SWZ(row, colw)] = (_Float16)y[r];
        }
    }
    if (tid < 256) {
        int row = tid >> 4, col = 112 + (tid & 15);
        sH1[row * 128 + SWZ(row, col)] = (_Float16)0.f;
    }
    {
        int row = tid >> 5, cc = tid & 31;
        int col = (cc < 16) ? (112 + cc) : (224 + cc);
        sZR[row * 256 + SWZ(row, col)] = (_Float16)0.f;
    }
    __syncthreads();

    const float t0 = ts[0], t1 = ts[1];

    // running pointer for this thread's x element (row = tid>>5, c = tid&31), t = s+1
    const int xrow = tid >> 5, xc = tid & 31;
    const float* xptr = data + (size_t)(m0 + xrow) * (T_STEPS * 32) + 32 + xc;
    const int xsw = xrow * 128 + SWZ(xrow, 64 + xc);

    #pragma unroll 1
    for (int s = 0; s < T_STEPS - 1; ++s) {
        const float dt = (s == 0) ? (t1 - t0) : (ts[s - 1] - ts[s]);
        float xv = *xptr; xptr += 32;

        // ---- G1: H1 = tanh(y @ Wo1 + bo1)  — wave w<7 owns tile nt=w ----
        if (wv < 7) {
            f16x8 a0 = ldsA(sYb, 64, c16, (g4 << 3));
            f16x8 a1 = ldsA(sYb, 64, c16, 32 + (g4 << 3));
            f32x4 z4 = {0.f, 0.f, 0.f, 0.f};
            f32x4 acc0 = MFMA16(a0, Pt[(wv * 2 + 0) * 64 + lane], z4);
            f32x4 acc1 = MFMA16(a1, Pt[(wv * 2 + 1) * 64 + lane], z4);
            int col = wv * 16 + c16;
            #pragma unroll
            for (int r = 0; r < 4; ++r) {
                int row = g4 * 4 + r;
                sH1[row * 128 + SWZ(row, col)] = (_Float16)fast_tanh(acc0[r] + acc1[r] + b_o1);
            }
        }
        // stage x into both concat buffers (one elem per thread)
        {
            _Float16 xh = (_Float16)xv;
            sYX[xsw] = xh; sRX[xsw] = xh;
        }
        __syncthreads();

        // ---- G2: yode = y + dt*(H1 @ Wo2 + bo2) — waves 0-3 ----
        float yo[4] = {0.f, 0.f, 0.f, 0.f};
        if (wv < 4) {
            f32x4 z4 = {0.f, 0.f, 0.f, 0.f};
            f32x4 acc0 = z4, acc1 = z4;
            acc0 = MFMA16(ldsA(sH1, 128, c16, 0 * 32 + (g4 << 3)), Bo2[0], acc0);
            acc1 = MFMA16(ldsA(sH1, 128, c16, 1 * 32 + (g4 << 3)), Bo2[1], acc1);
            acc0 = MFMA16(ldsA(sH1, 128, c16, 2 * 32 + (g4 << 3)), Bo2[2], acc0);
            acc1 = MFMA16(ldsA(sH1, 128, c16, 3 * 32 + (g4 << 3)), Bo2[3], acc1);
            #pragma unroll
            for (int r = 0; r < 4; ++r) {
                int row = g4 * 4 + r;
                yo[r] = y[r] + dt * (acc0[r] + acc1[r] + b_o2);
                sYO[row * 64 + colw] = yo[r];
                sYX[row * 128 + SWZ(row, colw)] = (_Float16)yo[r];
            }
        }
        __syncthreads();

        // ---- G3: zr-hidden = tanh([yode|x] @ W{z,r}1 + b) — tiles {wv, wv+8} ----
        {
            f16x8 a0 = ldsA(sYX, 128, c16, 0 * 32 + (g4 << 3));
            f16x8 a1 = ldsA(sYX, 128, c16, 1 * 32 + (g4 << 3));
            f16x8 a2 = ldsA(sYX, 128, c16, 2 * 32 + (g4 << 3));
            f32x4 z4 = {0.f, 0.f, 0.f, 0.f};
            {   // tile A: t = wv
                int bt = (wv < 7) ? wv : wv + 1;
                f32x4 acc0 = MFMA16(a0, Pt[(30 + bt * 3 + 0) * 64 + lane], z4);
                f32x4 acc1 = MFMA16(a1, Pt[(30 + bt * 3 + 1) * 64 + lane], z4);
                acc0 = MFMA16(a2, Pt[(30 + bt * 3 + 2) * 64 + lane], acc0);
                int col = bt * 16 + c16;
                #pragma unroll
                for (int r = 0; r < 4; ++r) {
                    int row = g4 * 4 + r;
                    sZR[row * 256 + SWZ(row, col)] = (_Float16)fast_tanh(acc0[r] + acc1[r] + b_zr0);
                }
            }
            if (wv < 6) {   // tile B: t = wv+8 (always r-gate), bt = t+1
                int bt = wv + 9;
                f32x4 acc0 = MFMA16(a0, Pt[(30 + bt * 3 + 0) * 64 + lane], z4);
                f32x4 acc1 = MFMA16(a1, Pt[(30 + bt * 3 + 1) * 64 + lane], z4);
                acc0 = MFMA16(a2, Pt[(30 + bt * 3 + 2) * 64 + lane], acc0);
                int col = bt * 16 + c16;
                #pragma unroll
                for (int r = 0; r < 4; ++r) {
                    int row = g4 * 4 + r;
                    sZR[row * 256 + SWZ(row, col)] = (_Float16)fast_tanh(acc0[r] + acc1[r] + b_zr1);
                }
            }
        }
        __syncthreads();

        // ---- G4: z-gate (waves 0-3, into regs) ; r-gate (waves 4-7, into sRX) ----
        float zg[4] = {0.f, 0.f, 0.f, 0.f};
        {
            int half = (wv < 4) ? 0 : 128;
            f32x4 z4 = {0.f, 0.f, 0.f, 0.f};
            f32x4 acc0 = z4, acc1 = z4;
            acc0 = MFMA16(ldsA(sZR, 256, c16, half + 0 * 32 + (g4 << 3)), Bzr[0], acc0);
            acc1 = MFMA16(ldsA(sZR, 256, c16, half + 1 * 32 + (g4 << 3)), Bzr[1], acc1);
            acc0 = MFMA16(ldsA(sZR, 256, c16, half + 2 * 32 + (g4 << 3)), Bzr[2], acc0);
            acc1 = MFMA16(ldsA(sZR, 256, c16, half + 3 * 32 + (g4 << 3)), Bzr[3], acc1);
            if (wv < 4) {
                #pragma unroll
                for (int r = 0; r < 4; ++r) zg[r] = fast_sigmoid(acc0[r] + acc1[r] + b_z2);
            } else {
                #pragma unroll
                for (int r = 0; r < 4; ++r) {
                    int row = g4 * 4 + r;
                    float yov = sYO[row * 64 + colw];
                    float rv = fast_sigmoid(acc0[r] + acc1[r] + b_r2) * yov;
                    sRX[row * 128 + SWZ(row, colw)] = (_Float16)rv;
                }
            }
        }
        __syncthreads();

        // ---- G5: H1 = tanh([rg*yode|x] @ Wh1 + bh1) — wave w<7 owns tile nt=w ----
        if (wv < 7) {
            f16x8 a0 = ldsA(sRX, 128, c16, 0 * 32 + (g4 << 3));
            f16x8 a1 = ldsA(sRX, 128, c16, 1 * 32 + (g4 << 3));
            f16x8 a2 = ldsA(sRX, 128, c16, 2 * 32 + (g4 << 3));
            f32x4 z4 = {0.f, 0.f, 0.f, 0.f};
            f32x4 acc0 = MFMA16(a0, Pt[(107 + wv * 3 + 0) * 64 + lane], z4);
            f32x4 acc1 = MFMA16(a1, Pt[(107 + wv * 3 + 1) * 64 + lane], z4);
            acc0 = MFMA16(a2, Pt[(107 + wv * 3 + 2) * 64 + lane], acc0);
            int col = wv * 16 + c16;
            #pragma unroll
            for (int r = 0; r < 4; ++r) {
                int row = g4 * 4 + r;
                sH1[row * 128 + SWZ(row, col)] = (_Float16)fast_tanh(acc0[r] + acc1[r] + b_h1);
            }
        }
        __syncthreads();

        // ---- G6: h = tanh(H1 @ Wh2 + bh2); y = (1-z)*h + z*yode — waves 0-3 ----
        if (wv < 4) {
            f32x4 z4 = {0.f, 0.f, 0.f, 0.f};
            f32x4 acc0 = z4, acc1 = z4;
            acc0 = MFMA16(ldsA(sH1, 128, c16, 0 * 32 + (g4 << 3)), Bh2[0], acc0);
            acc1 = MFMA16(ldsA(sH1, 128, c16, 1 * 32 + (g4 << 3)), Bh2[1], acc1);
            acc0 = MFMA16(ldsA(sH1, 128, c16, 2 * 32 + (g4 << 3)), Bh2[2], acc0);
            acc1 = MFMA16(ldsA(sH1, 128, c16, 3 * 32 + (g4 << 3)), Bh2[3], acc1);
            #pragma unroll
            for (int r = 0; r < 4; ++r) {
                int row = g4 * 4 + r;
                float h = fast_tanh(acc0[r] + acc1[r] + b_h2);
                y[r] = (1.f - zg[r]) * h + zg[r] * yo[r];
                sYb[row * 64 + SWZ(row, colw)] = (_Float16)y[r];
            }
        }
        __syncthreads();
    }

    if (wv < 4) {
        #pragma unroll
        for (int r = 0; r < 4; ++r) {
            int row = g4 * 4 + r;
            out[(size_t)(m0 + row) * 64 + colw] = y[r];
        }
    }
}

extern "C" void kernel_launch(void* const* d_in, const int* in_sizes, int n_in,
                              void* d_out, int out_size, void* d_ws, size_t ws_size,
                              hipStream_t stream) {
    const float* data = (const float*)d_in[0];
    const float* ts   = (const float*)d_in[1];
    const float* prior= (const float*)d_in[2];
    const float* Wo1 = (const float*)d_in[3];  const float* bo1 = (const float*)d_in[4];
    const float* Wo2 = (const float*)d_in[5];  const float* bo2 = (const float*)d_in[6];
    const float* Wz1 = (const float*)d_in[7];  const float* bz1 = (const float*)d_in[8];
    const float* Wz2 = (const float*)d_in[9];  const float* bz2 = (const float*)d_in[10];
    const float* Wr1 = (const float*)d_in[11]; const float* br1 = (const float*)d_in[12];
    const float* Wr2 = (const float*)d_in[13]; const float* br2 = (const float*)d_in[14];
    const float* Wh1 = (const float*)d_in[15]; const float* bh1 = (const float*)d_in[16];
    const float* Wh2 = (const float*)d_in[17]; const float* bh2 = (const float*)d_in[18];
    _Float16* P = (_Float16*)d_ws;
    float* out = (float*)d_out;

    hipLaunchKernelGGL(pack_kernel, dim3((144 * 512 + 255) / 256), dim3(256), 0, stream,
                       Wo1, Wo2, Wz1, Wz2, Wr1, Wr2, Wh1, Wh2, P);
    hipLaunchKernelGGL(odernn_kernel, dim3(NTRAJ / MBLK), dim3(512), 0, stream,
                       data, ts, prior, bo1, bo2, bz1, bz2, br1, br2, bh1, bh2, P, out);
}